// Round 1
// baseline (319.707 us; speedup 1.0000x reference)
//
#include <hip/hip_runtime.h>

#define TCHUNK 32   // timesteps per chunk (per K2 wave)

// ---------------------------------------------------------------------------
// K1: per-chunk per-channel partial sums.  S[b][ch][c] = sum_{t in chunk} x
// grid (nch, B), block 256 threads, thread -> 4 contiguous channels (float4)
// ---------------------------------------------------------------------------
__global__ __launch_bounds__(256) void k_chunk_sums(const float* __restrict__ x,
                                                    float* __restrict__ S,
                                                    int T, int C, int nch) {
    const int ch = blockIdx.x;
    const int b  = blockIdx.y;
    const int c  = threadIdx.x * 4;
    const float* xp = x + ((size_t)(b * T + ch * TCHUNK) * C + c);
    float sx = 0.f, sy = 0.f, sz = 0.f, sw = 0.f;
#pragma unroll
    for (int i = 0; i < TCHUNK; ++i) {
        float4 v = *(const float4*)(xp + (size_t)i * C);
        sx += v.x; sy += v.y; sz += v.z; sw += v.w;
    }
    float4 s = make_float4(sx, sy, sz, sw);
    *(float4*)(S + ((size_t)(b * nch + ch) * C + c)) = s;
}

// ---------------------------------------------------------------------------
// K1.5: in-place EXCLUSIVE scan of S along the chunk axis, per (b,c) column.
// One thread per (b,c).  After this, S[b][ch][c] = sum of chunks < ch.
// ---------------------------------------------------------------------------
__global__ __launch_bounds__(256) void k_scan(float* __restrict__ S, int C, int nch) {
    const int idx = blockIdx.x * 256 + threadIdx.x;  // 0 .. B*C-1
    const int b = idx / C;
    const int c = idx - b * C;
    float* p = S + (size_t)b * nch * C + c;
    float run = 0.f;
    for (int j = 0; j < nch; ++j) {
        float v = p[(size_t)j * C];
        p[(size_t)j * C] = run;
        run += v;
    }
}

// ---------------------------------------------------------------------------
// K2: one wave (64 lanes) per (b, chunk).  Lane owns 16 channels:
//     c(q) = q*256 + lane*4 .. +3   (4 coalesced float4 loads cover C=1024)
// Sequentially walks TCHUNK timesteps: running sum += x, mean = run/(t+1)
// (t==0 -> mean 0), xc = x - mean, wave-wide butterfly reduce of xc^2,
// scale = rsqrt(var + eps), store weight * xc * scale.
// ---------------------------------------------------------------------------
__global__ __launch_bounds__(64) void k_norm(const float* __restrict__ x,
                                             const float* __restrict__ P,
                                             const float* __restrict__ w,
                                             float* __restrict__ out,
                                             int T, int C, int nch) {
    const int ch   = blockIdx.x;
    const int b    = blockIdx.y;
    const int lane = threadIdx.x;
    const int cb   = lane * 4;

    float4 run[4], wt[4];
    const float* Pp = P + (size_t)(b * nch + ch) * C;
#pragma unroll
    for (int q = 0; q < 4; ++q) {
        run[q] = *(const float4*)(Pp + q * 256 + cb);
        wt[q]  = *(const float4*)(w + q * 256 + cb);
    }

    const int t0 = ch * TCHUNK;
    const float* xp = x   + (size_t)(b * T + t0) * C;
    float*       op = out + (size_t)(b * T + t0) * C;
    const float invC = 1.0f / (float)C;

#pragma unroll 2
    for (int i = 0; i < TCHUNK; ++i) {
        const int t = t0 + i;
        float4 xv[4];
#pragma unroll
        for (int q = 0; q < 4; ++q)
            xv[q] = *(const float4*)(xp + (size_t)i * C + q * 256 + cb);

        const float invc = 1.0f / (float)(t + 1);
        const float m = (t == 0) ? 0.0f : invc;

        float4 xc[4];
        float sq = 0.f;
#pragma unroll
        for (int q = 0; q < 4; ++q) {
            run[q].x += xv[q].x;  xc[q].x = xv[q].x - run[q].x * m;  sq += xc[q].x * xc[q].x;
            run[q].y += xv[q].y;  xc[q].y = xv[q].y - run[q].y * m;  sq += xc[q].y * xc[q].y;
            run[q].z += xv[q].z;  xc[q].z = xv[q].z - run[q].z * m;  sq += xc[q].z * xc[q].z;
            run[q].w += xv[q].w;  xc[q].w = xv[q].w - run[q].w * m;  sq += xc[q].w * xc[q].w;
        }

        // full 64-lane butterfly sum
#pragma unroll
        for (int off = 32; off; off >>= 1)
            sq += __shfl_xor(sq, off, 64);

        const float scale = rsqrtf(sq * invC + 1e-5f);

#pragma unroll
        for (int q = 0; q < 4; ++q) {
            float4 o;
            o.x = wt[q].x * xc[q].x * scale;
            o.y = wt[q].y * xc[q].y * scale;
            o.z = wt[q].z * xc[q].z * scale;
            o.w = wt[q].w * xc[q].w * scale;
            *(float4*)(op + (size_t)i * C + q * 256 + cb) = o;
        }
    }
}

extern "C" void kernel_launch(void* const* d_in, const int* in_sizes, int n_in,
                              void* d_out, int out_size, void* d_ws, size_t ws_size,
                              hipStream_t stream) {
    const float* x = (const float*)d_in[0];
    const float* w = (const float*)d_in[1];
    float* out = (float*)d_out;

    const int C = in_sizes[1];              // 1024
    const int T = 8192;
    const int B = in_sizes[0] / (T * C);    // 4
    const int nch = T / TCHUNK;             // 256

    float* S = (float*)d_ws;                // B*nch*C floats = 4 MB scratch

    dim3 g1(nch, B);
    k_chunk_sums<<<g1, 256, 0, stream>>>(x, S, T, C, nch);

    const int bc = B * C;
    k_scan<<<(bc + 255) / 256, 256, 0, stream>>>(S, C, nch);

    dim3 g2(nch, B);
    k_norm<<<g2, 64, 0, stream>>>(x, S, w, out, T, C, nch);
}

// Round 2
// 265.171 us; speedup vs baseline: 1.2057x; 1.2057x over previous
//
#include <hip/hip_runtime.h>

#define T_    8192
#define C_    1024
#define TCH   8          // timesteps per chunk (one wave per chunk in K2)
#define NCH   (T_ / TCH) // 1024 chunks
#define SBS   32         // chunks per superblock
#define NSB   (NCH / SBS) // 32 superblocks

// ---------------------------------------------------------------------------
// K1: per-chunk per-channel sums. S[b][ch][c] = sum of TCH timesteps.
// grid (NCH, B), block 256; thread -> 4 contiguous channels (float4).
// ---------------------------------------------------------------------------
__global__ __launch_bounds__(256) void k_chunk_sums(const float* __restrict__ x,
                                                    float* __restrict__ S) {
    const int ch = blockIdx.x;
    const int b  = blockIdx.y;
    const int c  = threadIdx.x * 4;
    const float* xp = x + ((size_t)(b * T_ + ch * TCH) * C_ + c);
    float4 s = make_float4(0.f, 0.f, 0.f, 0.f);
#pragma unroll
    for (int i = 0; i < TCH; ++i) {
        float4 v = *(const float4*)(xp + (size_t)i * C_);
        s.x += v.x; s.y += v.y; s.z += v.z; s.w += v.w;
    }
    *(float4*)(S + ((size_t)(b * NCH + ch) * C_ + c)) = s;
}

// ---------------------------------------------------------------------------
// scan_a: in-place EXCLUSIVE scan of S within each superblock (SBS chunks),
// per (b, sb, c). Writes superblock total to S2[b][sb][c].
// flat thread id -> (b, sb, c); coalesced across c.
// ---------------------------------------------------------------------------
__global__ __launch_bounds__(256) void k_scan_a(float* __restrict__ S,
                                                float* __restrict__ S2) {
    const int idx = blockIdx.x * 256 + threadIdx.x;   // 0 .. B*NSB*C-1
    const int c   = idx & (C_ - 1);
    const int sb  = (idx >> 10) & (NSB - 1);
    const int b   = idx >> 15;                        // /(C_*NSB)
    float* p = S + ((size_t)(b * NCH + sb * SBS) * C_ + c);
    float run = 0.f;
#pragma unroll 4
    for (int j = 0; j < SBS; ++j) {
        float v = p[(size_t)j * C_];
        p[(size_t)j * C_] = run;
        run += v;
    }
    S2[(size_t)(b * NSB + sb) * C_ + c] = run;
}

// ---------------------------------------------------------------------------
// scan_b: in-place EXCLUSIVE scan of S2 across the NSB superblocks, per (b,c).
// B*C = 4096 threads. Small (512 KB), latency-tolerant.
// ---------------------------------------------------------------------------
__global__ __launch_bounds__(256) void k_scan_b(float* __restrict__ S2) {
    const int idx = blockIdx.x * 256 + threadIdx.x;   // 0 .. B*C-1
    const int c = idx & (C_ - 1);
    const int b = idx >> 10;
    float* p = S2 + ((size_t)b * NSB * C_ + c);
    float run = 0.f;
#pragma unroll 4
    for (int j = 0; j < NSB; ++j) {
        float v = p[(size_t)j * C_];
        p[(size_t)j * C_] = run;
        run += v;
    }
}

// ---------------------------------------------------------------------------
// K2: block = 256 thr = 4 waves; wave w handles chunk ch = blockIdx.x*4 + w.
// Lane owns 16 channels: cq = q*256 + lane*4 (4 coalesced float4 per step).
// prefix = S2[b][ch/SBS][c] + S[b][ch][c]; walk TCH timesteps with running
// sum; wave-wide butterfly for variance; store weight * xc * rsqrt.
// ---------------------------------------------------------------------------
__global__ __launch_bounds__(256) void k_norm(const float* __restrict__ x,
                                              const float* __restrict__ S,
                                              const float* __restrict__ S2,
                                              const float* __restrict__ w,
                                              float* __restrict__ out) {
    const int wave = threadIdx.x >> 6;
    const int lane = threadIdx.x & 63;
    const int ch   = blockIdx.x * 4 + wave;
    const int b    = blockIdx.y;
    const int cb   = lane * 4;

    float4 run[4], wt[4];
    const float* Pp  = S  + (size_t)(b * NCH + ch) * C_;
    const float* P2p = S2 + (size_t)(b * NSB + (ch / SBS)) * C_;
#pragma unroll
    for (int q = 0; q < 4; ++q) {
        float4 a  = *(const float4*)(Pp  + q * 256 + cb);
        float4 bb = *(const float4*)(P2p + q * 256 + cb);
        run[q] = make_float4(a.x + bb.x, a.y + bb.y, a.z + bb.z, a.w + bb.w);
        wt[q]  = *(const float4*)(w + q * 256 + cb);
    }

    const int t0 = ch * TCH;
    const float* xp = x   + (size_t)(b * T_ + t0) * C_;
    float*       op = out + (size_t)(b * T_ + t0) * C_;
    const float invC = 1.0f / (float)C_;

#pragma unroll
    for (int i = 0; i < TCH; ++i) {
        const int t = t0 + i;
        float4 xv[4];
#pragma unroll
        for (int q = 0; q < 4; ++q)
            xv[q] = *(const float4*)(xp + (size_t)i * C_ + q * 256 + cb);

        const float m = (t == 0) ? 0.0f : 1.0f / (float)(t + 1);

        float4 xc[4];
        float sq = 0.f;
#pragma unroll
        for (int q = 0; q < 4; ++q) {
            run[q].x += xv[q].x;  xc[q].x = xv[q].x - run[q].x * m;  sq += xc[q].x * xc[q].x;
            run[q].y += xv[q].y;  xc[q].y = xv[q].y - run[q].y * m;  sq += xc[q].y * xc[q].y;
            run[q].z += xv[q].z;  xc[q].z = xv[q].z - run[q].z * m;  sq += xc[q].z * xc[q].z;
            run[q].w += xv[q].w;  xc[q].w = xv[q].w - run[q].w * m;  sq += xc[q].w * xc[q].w;
        }

#pragma unroll
        for (int off = 32; off; off >>= 1)
            sq += __shfl_xor(sq, off, 64);

        const float scale = rsqrtf(sq * invC + 1e-5f);

#pragma unroll
        for (int q = 0; q < 4; ++q) {
            float4 o;
            o.x = wt[q].x * xc[q].x * scale;
            o.y = wt[q].y * xc[q].y * scale;
            o.z = wt[q].z * xc[q].z * scale;
            o.w = wt[q].w * xc[q].w * scale;
            *(float4*)(op + (size_t)i * C_ + q * 256 + cb) = o;
        }
    }
}

extern "C" void kernel_launch(void* const* d_in, const int* in_sizes, int n_in,
                              void* d_out, int out_size, void* d_ws, size_t ws_size,
                              hipStream_t stream) {
    const float* x = (const float*)d_in[0];
    const float* w = (const float*)d_in[1];
    float* out = (float*)d_out;

    const int B = in_sizes[0] / (T_ * C_);            // 4

    float* S  = (float*)d_ws;                         // B*NCH*C floats = 16 MB
    float* S2 = S + (size_t)B * NCH * C_;             // B*NSB*C floats = 512 KB

    dim3 g1(NCH, B);
    k_chunk_sums<<<g1, 256, 0, stream>>>(x, S);

    const int na = B * NSB * C_;                      // 128K threads
    k_scan_a<<<na / 256, 256, 0, stream>>>(S, S2);

    const int nb = B * C_;                            // 4096 threads
    k_scan_b<<<nb / 256, 256, 0, stream>>>(S2);

    dim3 g2(NCH / 4, B);
    k_norm<<<g2, 256, 0, stream>>>(x, S, S2, w, out);
}